// Round 1
// baseline (661.676 us; speedup 1.0000x reference)
//
#include <hip/hip_runtime.h>

#define NN 50000
#define EE 300000
#define ET (EE + NN)   // edges + self loops = 350000
#define CD 256

// ---------------- CSR build ----------------

__global__ void init_deg_kernel(int* __restrict__ deg) {
    int i = blockIdx.x * blockDim.x + threadIdx.x;
    if (i < NN) deg[i] = 1;  // self loop
}

__global__ void count_deg_kernel(const int* __restrict__ ei, int* __restrict__ deg) {
    int i = blockIdx.x * blockDim.x + threadIdx.x;
    if (i < EE) atomicAdd(&deg[ei[EE + i]], 1);  // dst row of edge_index
}

__global__ __launch_bounds__(1024) void scan_kernel(const int* __restrict__ deg,
                                                    int* __restrict__ row_start,
                                                    int* __restrict__ fill_pos) {
    __shared__ int sums[1024];
    int t = threadIdx.x;
    const int CH = (NN + 1023) / 1024;  // 49
    int start = t * CH;
    int end = start + CH;
    if (end > NN) end = NN;
    int s = 0;
    for (int i = start; i < end; ++i) s += deg[i];
    sums[t] = s;
    __syncthreads();
    // inclusive Hillis-Steele scan over 1024 partials
    for (int off = 1; off < 1024; off <<= 1) {
        int v = sums[t];
        int vo = (t >= off) ? sums[t - off] : 0;
        __syncthreads();
        sums[t] = v + vo;
        __syncthreads();
    }
    int prefix = (t == 0) ? 0 : sums[t - 1];
    for (int i = start; i < end; ++i) {
        row_start[i] = prefix;
        fill_pos[i] = prefix;
        prefix += deg[i];
    }
    if (t == 1023) row_start[NN] = sums[1023];
}

__global__ void fill_csr_kernel(const int* __restrict__ ei, int* __restrict__ fill_pos,
                                int* __restrict__ srcs) {
    int i = blockIdx.x * blockDim.x + threadIdx.x;
    if (i < EE) {
        int s = ei[i];
        int d = ei[EE + i];
        int p = atomicAdd(&fill_pos[d], 1);
        srcs[p] = s;
    } else if (i < ET) {
        int n = i - EE;
        int p = atomicAdd(&fill_pos[n], 1);
        srcs[p] = n;  // self loop
    }
}

// ---------------- GEMM: C[M,256] = A[M,256] @ B (opt B^T), + bias, opt relu ----------------

template <int TRANSB, int RELU>
__global__ __launch_bounds__(256) void gemm64(const float* __restrict__ A,
                                              const float* __restrict__ B,
                                              const float* __restrict__ bias,
                                              float* __restrict__ Cout, int M) {
    const int K = CD;
    __shared__ float As[16][68];  // [k][m], padded
    __shared__ float Bs[16][68];  // [k][n], padded
    int tid = threadIdx.x;
    int bm = blockIdx.x * 64;
    int bn = blockIdx.y * 64;
    int tx = tid & 15, ty = tid >> 4;

    float acc[4][4];
#pragma unroll
    for (int i = 0; i < 4; ++i)
#pragma unroll
        for (int j = 0; j < 4; ++j) acc[i][j] = 0.f;

    int ar = tid >> 2, ak = (tid & 3) << 2;  // A tile: 64 rows x 16 k

    for (int k0 = 0; k0 < K; k0 += 16) {
        int arow = bm + ar;
        float4 av = make_float4(0.f, 0.f, 0.f, 0.f);
        if (arow < M) av = *(const float4*)(A + (size_t)arow * K + k0 + ak);
        As[ak + 0][ar] = av.x;
        As[ak + 1][ar] = av.y;
        As[ak + 2][ar] = av.z;
        As[ak + 3][ar] = av.w;
        if (!TRANSB) {
            int br = tid >> 4, bc = (tid & 15) << 2;  // 16 k-rows x 64 n-cols
            float4 bv = *(const float4*)(B + (size_t)(k0 + br) * K + bn + bc);
            Bs[br][bc + 0] = bv.x;
            Bs[br][bc + 1] = bv.y;
            Bs[br][bc + 2] = bv.z;
            Bs[br][bc + 3] = bv.w;
        } else {
            int bnr = tid >> 2, bk = (tid & 3) << 2;  // 64 n-rows x 16 k
            float4 bv = *(const float4*)(B + (size_t)(bn + bnr) * K + k0 + bk);
            Bs[bk + 0][bnr] = bv.x;
            Bs[bk + 1][bnr] = bv.y;
            Bs[bk + 2][bnr] = bv.z;
            Bs[bk + 3][bnr] = bv.w;
        }
        __syncthreads();
#pragma unroll
        for (int kk = 0; kk < 16; ++kk) {
            float a[4], b[4];
#pragma unroll
            for (int i = 0; i < 4; ++i) a[i] = As[kk][ty * 4 + i];
#pragma unroll
            for (int j = 0; j < 4; ++j) b[j] = Bs[kk][tx * 4 + j];
#pragma unroll
            for (int i = 0; i < 4; ++i)
#pragma unroll
                for (int j = 0; j < 4; ++j) acc[i][j] += a[i] * b[j];
        }
        __syncthreads();
    }

#pragma unroll
    for (int i = 0; i < 4; ++i) {
        int row = bm + ty * 4 + i;
        if (row >= M) continue;
        int col = bn + tx * 4;
        float4 v;
        v.x = acc[i][0];
        v.y = acc[i][1];
        v.z = acc[i][2];
        v.w = acc[i][3];
        if (bias) {
            v.x += bias[col + 0];
            v.y += bias[col + 1];
            v.z += bias[col + 2];
            v.w += bias[col + 3];
        }
        if (RELU) {
            v.x = fmaxf(v.x, 0.f);
            v.y = fmaxf(v.y, 0.f);
            v.z = fmaxf(v.z, 0.f);
            v.w = fmaxf(v.w, 0.f);
        }
        *(float4*)(Cout + (size_t)row * K + col) = v;
    }
}

// ---------------- per-node alpha dot products ----------------

__global__ __launch_bounds__(256) void alpha_kernel(const float* __restrict__ h,
                                                    const float* __restrict__ a_src,
                                                    const float* __restrict__ a_dst,
                                                    float* __restrict__ as_,
                                                    float* __restrict__ ad_) {
    int node = blockIdx.x * (blockDim.x >> 6) + (threadIdx.x >> 6);
    int lane = threadIdx.x & 63;
    if (node >= NN) return;
    float4 hv = *(const float4*)(h + (size_t)node * CD + lane * 4);
    float4 s4 = *(const float4*)(a_src + lane * 4);
    float4 d4 = *(const float4*)(a_dst + lane * 4);
    float ss = hv.x * s4.x + hv.y * s4.y + hv.z * s4.z + hv.w * s4.w;
    float dd = hv.x * d4.x + hv.y * d4.y + hv.z * d4.z + hv.w * d4.w;
    for (int off = 32; off > 0; off >>= 1) {
        ss += __shfl_down(ss, off);
        dd += __shfl_down(dd, off);
    }
    if (lane == 0) {
        as_[node] = ss;
        ad_[node] = dd;
    }
}

// ---------------- GAT aggregation: one wave per dst node ----------------

__device__ __forceinline__ float lrelu02(float x) { return x > 0.f ? x : 0.2f * x; }

template <int RELU>
__global__ __launch_bounds__(256) void gat_agg(const float* __restrict__ h,
                                               const float* __restrict__ as_,
                                               const float* __restrict__ ad_,
                                               const int* __restrict__ row_start,
                                               const int* __restrict__ srcs,
                                               const float* __restrict__ bias,
                                               float* __restrict__ out) {
    int node = blockIdx.x * (blockDim.x >> 6) + (threadIdx.x >> 6);
    int lane = threadIdx.x & 63;
    if (node >= NN) return;
    int rs = row_start[node];
    int re = row_start[node + 1];
    float adst = ad_[node];

    // phase 1a: segment max
    float m = -1e30f;
    for (int k = rs + lane; k < re; k += 64) {
        float e = lrelu02(as_[srcs[k]] + adst);
        m = fmaxf(m, e);
    }
    for (int off = 32; off > 0; off >>= 1) m = fmaxf(m, __shfl_down(m, off));
    m = __shfl(m, 0);

    // phase 1b: segment sum of exp
    float den = 0.f;
    for (int k = rs + lane; k < re; k += 64) {
        float e = lrelu02(as_[srcs[k]] + adst);
        den += __expf(e - m);
    }
    for (int off = 32; off > 0; off >>= 1) den += __shfl_down(den, off);
    den = __shfl(den, 0);
    float inv_den = 1.f / den;

    // phase 2: weighted accumulate of h[src]
    float4 acc = make_float4(0.f, 0.f, 0.f, 0.f);
    for (int k = rs; k < re; ++k) {
        int s = srcs[k];
        float e = lrelu02(as_[s] + adst);  // broadcast load, redundant per lane
        float w = __expf(e - m) * inv_den;
        float4 hv = *(const float4*)(h + (size_t)s * CD + lane * 4);
        acc.x += w * hv.x;
        acc.y += w * hv.y;
        acc.z += w * hv.z;
        acc.w += w * hv.w;
    }
    float4 b4 = *(const float4*)(bias + lane * 4);
    acc.x += b4.x;
    acc.y += b4.y;
    acc.z += b4.z;
    acc.w += b4.w;
    if (RELU) {
        acc.x = fmaxf(acc.x, 0.f);
        acc.y = fmaxf(acc.y, 0.f);
        acc.z = fmaxf(acc.z, 0.f);
        acc.w = fmaxf(acc.w, 0.f);
    }
    *(float4*)(out + (size_t)node * CD + lane * 4) = acc;
}

// ---------------- launch ----------------

extern "C" void kernel_launch(void* const* d_in, const int* in_sizes, int n_in,
                              void* d_out, int out_size, void* d_ws, size_t ws_size,
                              hipStream_t stream) {
    const float* x = (const float*)d_in[0];
    const int* ei = (const int*)d_in[1];
    const float* W1 = (const float*)d_in[2];
    const float* a1s = (const float*)d_in[3];
    const float* a1d = (const float*)d_in[4];
    const float* b1 = (const float*)d_in[5];
    const float* W2 = (const float*)d_in[6];
    const float* a2s = (const float*)d_in[7];
    const float* a2d = (const float*)d_in[8];
    const float* b2 = (const float*)d_in[9];
    const float* Wl = (const float*)d_in[10];
    const float* bl = (const float*)d_in[11];
    float* out = (float*)d_out;

    float* hA = (float*)d_ws;              // NN*CD
    float* hB = hA + (size_t)NN * CD;      // NN*CD
    float* as_ = hB + (size_t)NN * CD;     // NN
    float* ad_ = as_ + NN;                 // NN
    int* deg = (int*)(ad_ + NN);           // NN
    int* row_start = deg + NN;             // NN+1
    int* fill_pos = row_start + NN + 1;    // NN
    int* srcs = fill_pos + NN;             // ET

    // CSR build
    init_deg_kernel<<<(NN + 255) / 256, 256, 0, stream>>>(deg);
    count_deg_kernel<<<(EE + 255) / 256, 256, 0, stream>>>(ei, deg);
    scan_kernel<<<1, 1024, 0, stream>>>(deg, row_start, fill_pos);
    fill_csr_kernel<<<(ET + 255) / 256, 256, 0, stream>>>(ei, fill_pos, srcs);

    dim3 ggrid((NN + 63) / 64, CD / 64);
    int nwave_blocks = (NN + 3) / 4;  // 4 waves (nodes) per 256-thread block

    // Layer 1
    gemm64<0, 0><<<ggrid, 256, 0, stream>>>(x, W1, nullptr, hA, NN);
    alpha_kernel<<<nwave_blocks, 256, 0, stream>>>(hA, a1s, a1d, as_, ad_);
    gat_agg<1><<<nwave_blocks, 256, 0, stream>>>(hA, as_, ad_, row_start, srcs, b1, hB);

    // Layer 2
    gemm64<0, 0><<<ggrid, 256, 0, stream>>>(hB, W2, nullptr, hA, NN);
    alpha_kernel<<<nwave_blocks, 256, 0, stream>>>(hA, a2s, a2d, as_, ad_);
    gat_agg<1><<<nwave_blocks, 256, 0, stream>>>(hA, as_, ad_, row_start, srcs, b2, hB);

    // Final linear: out = hB @ Wl^T + bl
    gemm64<1, 0><<<ggrid, 256, 0, stream>>>(hB, Wl, bl, out, NN);
}

// Round 2
// 370.974 us; speedup vs baseline: 1.7836x; 1.7836x over previous
//
#include <hip/hip_runtime.h>

#define NN 50000
#define EE 300000
#define ET (EE + NN)   // edges + self loops = 350000
#define CD 256
#define PAD_M 50048    // 391 * 128, covers gemm tile over-read
#define NB 196         // scan blocks: 196*256 = 50176 >= NN

typedef unsigned short ushortT;
typedef short bf16x8 __attribute__((ext_vector_type(8)));
typedef float f32x4 __attribute__((ext_vector_type(4)));

__device__ __forceinline__ ushortT f2b(float f) {
    unsigned u = __builtin_bit_cast(unsigned, f);
    unsigned r = (u + 0x7FFFu + ((u >> 16) & 1u)) >> 16;
    return (ushortT)r;
}
__device__ __forceinline__ float b2f(ushortT b) {
    return __builtin_bit_cast(float, ((unsigned)b) << 16);
}

// ---------------- CSR build ----------------

__global__ void init_deg_kernel(int* __restrict__ deg) {
    int i = blockIdx.x * blockDim.x + threadIdx.x;
    if (i < NN) deg[i] = 1;  // self loop
}

__global__ void count_deg_kernel(const int* __restrict__ ei, int* __restrict__ deg) {
    int i = blockIdx.x * blockDim.x + threadIdx.x;
    if (i < EE) atomicAdd(&deg[ei[EE + i]], 1);  // dst row of edge_index
}

__global__ __launch_bounds__(256) void scan_part(const int* __restrict__ deg,
                                                 int* __restrict__ bsum) {
    int i = blockIdx.x * 256 + threadIdx.x;
    int v = (i < NN) ? deg[i] : 0;
#pragma unroll
    for (int off = 32; off > 0; off >>= 1) v += __shfl_down(v, off);
    __shared__ int w[4];
    if ((threadIdx.x & 63) == 0) w[threadIdx.x >> 6] = v;
    __syncthreads();
    if (threadIdx.x == 0) bsum[blockIdx.x] = w[0] + w[1] + w[2] + w[3];
}

__global__ __launch_bounds__(256) void scan_top(const int* __restrict__ bsum,
                                                int* __restrict__ boffs,
                                                int* __restrict__ row_start) {
    __shared__ int s[256];
    int t = threadIdx.x;
    int v = (t < NB) ? bsum[t] : 0;
    s[t] = v;
    __syncthreads();
    for (int off = 1; off < 256; off <<= 1) {
        int x = s[t];
        int y = (t >= off) ? s[t - off] : 0;
        __syncthreads();
        s[t] = x + y;
        __syncthreads();
    }
    if (t < NB) boffs[t] = s[t] - v;  // exclusive
    if (t == 0) row_start[NN] = ET;
}

__global__ __launch_bounds__(256) void scan_fill(const int* __restrict__ deg,
                                                 const int* __restrict__ boffs,
                                                 int* __restrict__ row_start,
                                                 int* __restrict__ fill_pos) {
    __shared__ int s[256];
    int t = threadIdx.x;
    int i = blockIdx.x * 256 + t;
    int v = (i < NN) ? deg[i] : 0;
    s[t] = v;
    __syncthreads();
    for (int off = 1; off < 256; off <<= 1) {
        int x = s[t];
        int y = (t >= off) ? s[t - off] : 0;
        __syncthreads();
        s[t] = x + y;
        __syncthreads();
    }
    int excl = s[t] - v + boffs[blockIdx.x];
    if (i < NN) {
        row_start[i] = excl;
        fill_pos[i] = excl;
    }
}

__global__ void fill_csr_kernel(const int* __restrict__ ei, int* __restrict__ fill_pos,
                                int* __restrict__ srcs) {
    int i = blockIdx.x * blockDim.x + threadIdx.x;
    if (i < EE) {
        int s = ei[i];
        int d = ei[EE + i];
        int p = atomicAdd(&fill_pos[d], 1);
        srcs[p] = s;
    } else if (i < ET) {
        int n = i - EE;
        int p = atomicAdd(&fill_pos[n], 1);
        srcs[p] = n;  // self loop
    }
}

// ---------------- casts ----------------

__global__ __launch_bounds__(256) void cast_x_kernel(const float* __restrict__ in,
                                                     ushortT* __restrict__ out) {
    int id = blockIdx.x * 256 + threadIdx.x;  // one float4 per thread
    float4 v = *(const float4*)(in + (size_t)id * 4);
    ushort4 o;
    o.x = f2b(v.x);
    o.y = f2b(v.y);
    o.z = f2b(v.z);
    o.w = f2b(v.w);
    *(ushort4*)(out + (size_t)id * 4) = o;
}

// Bt[n][k] = W[k][n], bf16 out. grid (8,8), block 256 (32x8)
__global__ __launch_bounds__(256) void castT_kernel(const float* __restrict__ W,
                                                    ushortT* __restrict__ Bt) {
    __shared__ float t[32][33];
    int bx = blockIdx.x * 32;  // k base
    int by = blockIdx.y * 32;  // n base
    int x = threadIdx.x & 31, y = threadIdx.x >> 5;
    for (int yy = y; yy < 32; yy += 8) t[yy][x] = W[(size_t)(bx + yy) * CD + by + x];
    __syncthreads();
    for (int yy = y; yy < 32; yy += 8)
        Bt[(size_t)(by + yy) * CD + bx + x] = f2b(t[x][yy]);
}

// straight cast (Wl: out = hB @ Wl^T -> Bt[n][k] = Wl[n][k] directly)
__global__ __launch_bounds__(256) void cast_w_kernel(const float* __restrict__ W,
                                                     ushortT* __restrict__ Bt) {
    int id = blockIdx.x * 256 + threadIdx.x;
    float4 v = *(const float4*)(W + (size_t)id * 4);
    ushort4 o;
    o.x = f2b(v.x);
    o.y = f2b(v.y);
    o.z = f2b(v.z);
    o.w = f2b(v.w);
    *(ushort4*)(Bt + (size_t)id * 4) = o;
}

// ---------------- bf16 MFMA GEMM: C[M,256] = A[M,256] @ Bt^T ----------------
// A row-major bf16 [M][256]; Bt n-major k-contiguous bf16 [256][256].
// OUTF32=1: fp32 out + bias; OUTF32=0: bf16 out, no bias.

template <int OUTF32>
__global__ __launch_bounds__(256) void gemm_mfma(const ushortT* __restrict__ A,
                                                 const ushortT* __restrict__ Bt,
                                                 const float* __restrict__ bias,
                                                 float* __restrict__ outF,
                                                 ushortT* __restrict__ outB,
                                                 int M) {
    __shared__ ushortT As[128 * 32];
    __shared__ ushortT Bs[128 * 32];
    int tid = threadIdx.x;
    int wave = tid >> 6, lane = tid & 63;
    int wm = (wave >> 1) * 64, wn = (wave & 1) * 64;
    int bm = blockIdx.x * 128, bn = blockIdx.y * 128;
    int l15 = lane & 15, quad = lane >> 4;

    f32x4 acc[4][4] = {};

    for (int k0 = 0; k0 < CD; k0 += 32) {
#pragma unroll
        for (int p = 0; p < 2; ++p) {
            int c = p * 256 + wave * 64 + lane;
            int row = c >> 2, piece = c & 3;
            const ushortT* ga = A + (size_t)(bm + row) * CD + k0 + piece * 8;
            const ushortT* gb = Bt + (size_t)(bn + row) * CD + k0 + piece * 8;
            // wave-uniform LDS base; HW scatters lane i to base + i*16
            __builtin_amdgcn_global_load_lds(
                (const __attribute__((address_space(1))) void*)ga,
                (__attribute__((address_space(3))) void*)(As + (size_t)(p * 256 + wave * 64) * 8),
                16, 0, 0);
            __builtin_amdgcn_global_load_lds(
                (const __attribute__((address_space(1))) void*)gb,
                (__attribute__((address_space(3))) void*)(Bs + (size_t)(p * 256 + wave * 64) * 8),
                16, 0, 0);
        }
        __syncthreads();

        bf16x8 a[4], b[4];
#pragma unroll
        for (int i = 0; i < 4; ++i)
            a[i] = *(const bf16x8*)(As + (size_t)(wm + i * 16 + l15) * 32 + quad * 8);
#pragma unroll
        for (int j = 0; j < 4; ++j)
            b[j] = *(const bf16x8*)(Bs + (size_t)(wn + j * 16 + l15) * 32 + quad * 8);
#pragma unroll
        for (int i = 0; i < 4; ++i)
#pragma unroll
            for (int j = 0; j < 4; ++j)
                acc[i][j] = __builtin_amdgcn_mfma_f32_16x16x32_bf16(a[i], b[j], acc[i][j], 0, 0, 0);
        __syncthreads();
    }

#pragma unroll
    for (int i = 0; i < 4; ++i) {
#pragma unroll
        for (int j = 0; j < 4; ++j) {
            int col = bn + wn + j * 16 + l15;
            int row0 = bm + wm + i * 16 + quad * 4;
#pragma unroll
            for (int r = 0; r < 4; ++r) {
                int row = row0 + r;
                if (row < M) {
                    float v = acc[i][j][r];
                    if (OUTF32) {
                        v += bias[col];
                        outF[(size_t)row * CD + col] = v;
                    } else {
                        outB[(size_t)row * CD + col] = f2b(v);
                    }
                }
            }
        }
    }
}

// ---------------- per-node alpha dot products (bf16 h) ----------------

__global__ __launch_bounds__(256) void alpha_kernel(const ushortT* __restrict__ h,
                                                    const float* __restrict__ a_src,
                                                    const float* __restrict__ a_dst,
                                                    float* __restrict__ as_,
                                                    float* __restrict__ ad_) {
    int node = blockIdx.x * 4 + (threadIdx.x >> 6);
    int lane = threadIdx.x & 63;
    if (node >= NN) return;
    ushort4 hv = *(const ushort4*)(h + (size_t)node * CD + lane * 4);
    float h0 = b2f(hv.x), h1 = b2f(hv.y), h2 = b2f(hv.z), h3 = b2f(hv.w);
    float4 s4 = *(const float4*)(a_src + lane * 4);
    float4 d4 = *(const float4*)(a_dst + lane * 4);
    float ss = h0 * s4.x + h1 * s4.y + h2 * s4.z + h3 * s4.w;
    float dd = h0 * d4.x + h1 * d4.y + h2 * d4.z + h3 * d4.w;
    for (int off = 32; off > 0; off >>= 1) {
        ss += __shfl_down(ss, off);
        dd += __shfl_down(dd, off);
    }
    if (lane == 0) {
        as_[node] = ss;
        ad_[node] = dd;
    }
}

// ---------------- GAT aggregation: one wave per dst node (bf16 h, bf16 out) ----------------

__device__ __forceinline__ float lrelu02(float x) { return x > 0.f ? x : 0.2f * x; }

__global__ __launch_bounds__(256) void gat_agg(const ushortT* __restrict__ h,
                                               const float* __restrict__ as_,
                                               const float* __restrict__ ad_,
                                               const int* __restrict__ row_start,
                                               const int* __restrict__ srcs,
                                               const float* __restrict__ bias,
                                               ushortT* __restrict__ out) {
    int node = blockIdx.x * 4 + (threadIdx.x >> 6);
    int lane = threadIdx.x & 63;
    if (node >= NN) return;
    int rs = row_start[node];
    int re = row_start[node + 1];
    float adst = ad_[node];

    // phase 1a: segment max
    float m = -1e30f;
    for (int k = rs + lane; k < re; k += 64) {
        float e = lrelu02(as_[srcs[k]] + adst);
        m = fmaxf(m, e);
    }
    for (int off = 32; off > 0; off >>= 1) m = fmaxf(m, __shfl_down(m, off));
    m = __shfl(m, 0);

    // phase 1b: segment sum of exp
    float den = 0.f;
    for (int k = rs + lane; k < re; k += 64) {
        float e = lrelu02(as_[srcs[k]] + adst);
        den += __expf(e - m);
    }
    for (int off = 32; off > 0; off >>= 1) den += __shfl_down(den, off);
    den = __shfl(den, 0);
    float inv_den = 1.f / den;

    // phase 2: weighted accumulate of h[src]
    float a0 = 0.f, a1 = 0.f, a2 = 0.f, a3 = 0.f;
    for (int k = rs; k < re; ++k) {
        int s = srcs[k];
        float e = lrelu02(as_[s] + adst);  // broadcast load
        float w = __expf(e - m) * inv_den;
        ushort4 hv = *(const ushort4*)(h + (size_t)s * CD + lane * 4);
        a0 += w * b2f(hv.x);
        a1 += w * b2f(hv.y);
        a2 += w * b2f(hv.z);
        a3 += w * b2f(hv.w);
    }
    float4 b4 = *(const float4*)(bias + lane * 4);
    a0 = fmaxf(a0 + b4.x, 0.f);  // bias + relu (both convs feed relu)
    a1 = fmaxf(a1 + b4.y, 0.f);
    a2 = fmaxf(a2 + b4.z, 0.f);
    a3 = fmaxf(a3 + b4.w, 0.f);
    ushort4 o;
    o.x = f2b(a0);
    o.y = f2b(a1);
    o.z = f2b(a2);
    o.w = f2b(a3);
    *(ushort4*)(out + (size_t)node * CD + lane * 4) = o;
}

// ---------------- launch ----------------

extern "C" void kernel_launch(void* const* d_in, const int* in_sizes, int n_in,
                              void* d_out, int out_size, void* d_ws, size_t ws_size,
                              hipStream_t stream) {
    const float* x = (const float*)d_in[0];
    const int* ei = (const int*)d_in[1];
    const float* W1 = (const float*)d_in[2];
    const float* a1s = (const float*)d_in[3];
    const float* a1d = (const float*)d_in[4];
    const float* b1 = (const float*)d_in[5];
    const float* W2 = (const float*)d_in[6];
    const float* a2s = (const float*)d_in[7];
    const float* a2d = (const float*)d_in[8];
    const float* b2 = (const float*)d_in[9];
    const float* Wl = (const float*)d_in[10];
    const float* bl = (const float*)d_in[11];
    float* out = (float*)d_out;

    char* w = (char*)d_ws;
    ushortT* B0 = (ushortT*)w; w += (size_t)PAD_M * CD * 2;
    ushortT* B1 = (ushortT*)w; w += (size_t)PAD_M * CD * 2;
    ushortT* B2 = (ushortT*)w; w += (size_t)PAD_M * CD * 2;
    ushortT* W1t = (ushortT*)w; w += (size_t)CD * CD * 2;
    ushortT* W2t = (ushortT*)w; w += (size_t)CD * CD * 2;
    ushortT* Wlt = (ushortT*)w; w += (size_t)CD * CD * 2;
    float* as_ = (float*)w; w += (size_t)NN * 4;
    float* ad_ = (float*)w; w += (size_t)NN * 4;
    int* deg = (int*)w; w += (size_t)NN * 4;
    int* fill_pos = (int*)w; w += (size_t)NN * 4;
    int* srcs = (int*)w; w += (size_t)ET * 4;
    int* bsum = (int*)w; w += 1024;
    int* boffs = (int*)w; w += 1024;
    int* row_start = (int*)w; w += (size_t)(NN + 1) * 4;

    // CSR build
    init_deg_kernel<<<(NN + 255) / 256, 256, 0, stream>>>(deg);
    count_deg_kernel<<<(EE + 255) / 256, 256, 0, stream>>>(ei, deg);
    scan_part<<<NB, 256, 0, stream>>>(deg, bsum);
    scan_top<<<1, 256, 0, stream>>>(bsum, boffs, row_start);
    scan_fill<<<NB, 256, 0, stream>>>(deg, boffs, row_start, fill_pos);
    fill_csr_kernel<<<(ET + 255) / 256, 256, 0, stream>>>(ei, fill_pos, srcs);

    // casts
    cast_x_kernel<<<(NN * CD / 4) / 256, 256, 0, stream>>>(x, B0);
    castT_kernel<<<dim3(8, 8), 256, 0, stream>>>(W1, W1t);
    castT_kernel<<<dim3(8, 8), 256, 0, stream>>>(W2, W2t);
    cast_w_kernel<<<(CD * CD / 4) / 256, 256, 0, stream>>>(Wl, Wlt);

    dim3 ggrid((PAD_M) / 128, 2);
    int nwave_blocks = (NN + 3) / 4;

    // Layer 1
    gemm_mfma<0><<<ggrid, 256, 0, stream>>>(B0, W1t, nullptr, nullptr, B1, NN);
    alpha_kernel<<<nwave_blocks, 256, 0, stream>>>(B1, a1s, a1d, as_, ad_);
    gat_agg<<<nwave_blocks, 256, 0, stream>>>(B1, as_, ad_, row_start, srcs, b1, B2);

    // Layer 2
    gemm_mfma<0><<<ggrid, 256, 0, stream>>>(B2, W2t, nullptr, nullptr, B1, NN);
    alpha_kernel<<<nwave_blocks, 256, 0, stream>>>(B1, a2s, a2d, as_, ad_);
    gat_agg<<<nwave_blocks, 256, 0, stream>>>(B1, as_, ad_, row_start, srcs, b2, B0);

    // Final linear: out = B0 @ Wlt^T + bl (fp32 out)
    gemm_mfma<1><<<ggrid, 256, 0, stream>>>(B0, Wlt, bl, out, nullptr, NN);
}

// Round 3
// 319.990 us; speedup vs baseline: 2.0678x; 1.1593x over previous
//
#include <hip/hip_runtime.h>

#define NN 50000
#define EE 300000
#define ET (EE + NN)   // edges + self loops = 350000
#define CD 256
#define PAD_M 50048    // 391 * 128, covers gemm tile over-read
#define NB 196         // scan blocks: 196*256 = 50176 >= NN

typedef unsigned short ushortT;
typedef short bf16x8 __attribute__((ext_vector_type(8)));
typedef float f32x4 __attribute__((ext_vector_type(4)));

__device__ __forceinline__ ushortT f2b(float f) {
    unsigned u = __builtin_bit_cast(unsigned, f);
    unsigned r = (u + 0x7FFFu + ((u >> 16) & 1u)) >> 16;
    return (ushortT)r;
}
__device__ __forceinline__ float b2f(ushortT b) {
    return __builtin_bit_cast(float, ((unsigned)b) << 16);
}

// ---------------- CSR build ----------------

__global__ void init_kernel(int* __restrict__ deg, float* __restrict__ as_,
                            float* __restrict__ ad_) {
    int i = blockIdx.x * blockDim.x + threadIdx.x;
    if (i < NN) {
        deg[i] = 1;  // self loop
        as_[i] = 0.f;
        ad_[i] = 0.f;
    }
}

__global__ void zero_alpha_kernel(float* __restrict__ as_, float* __restrict__ ad_) {
    int i = blockIdx.x * blockDim.x + threadIdx.x;
    if (i < NN) {
        as_[i] = 0.f;
        ad_[i] = 0.f;
    }
}

__global__ void count_deg_kernel(const int* __restrict__ ei, int* __restrict__ deg) {
    int i = blockIdx.x * blockDim.x + threadIdx.x;
    if (i < EE) atomicAdd(&deg[ei[EE + i]], 1);  // dst row of edge_index
}

__global__ __launch_bounds__(256) void scan_part(const int* __restrict__ deg,
                                                 int* __restrict__ bsum) {
    int i = blockIdx.x * 256 + threadIdx.x;
    int v = (i < NN) ? deg[i] : 0;
#pragma unroll
    for (int off = 32; off > 0; off >>= 1) v += __shfl_down(v, off);
    __shared__ int w[4];
    if ((threadIdx.x & 63) == 0) w[threadIdx.x >> 6] = v;
    __syncthreads();
    if (threadIdx.x == 0) bsum[blockIdx.x] = w[0] + w[1] + w[2] + w[3];
}

__global__ __launch_bounds__(256) void scan_top(const int* __restrict__ bsum,
                                                int* __restrict__ boffs,
                                                int* __restrict__ row_start) {
    __shared__ int s[256];
    int t = threadIdx.x;
    int v = (t < NB) ? bsum[t] : 0;
    s[t] = v;
    __syncthreads();
    for (int off = 1; off < 256; off <<= 1) {
        int x = s[t];
        int y = (t >= off) ? s[t - off] : 0;
        __syncthreads();
        s[t] = x + y;
        __syncthreads();
    }
    if (t < NB) boffs[t] = s[t] - v;  // exclusive
    if (t == 0) row_start[NN] = ET;
}

__global__ __launch_bounds__(256) void scan_fill(const int* __restrict__ deg,
                                                 const int* __restrict__ boffs,
                                                 int* __restrict__ row_start,
                                                 int* __restrict__ fill_pos) {
    __shared__ int s[256];
    int t = threadIdx.x;
    int i = blockIdx.x * 256 + t;
    int v = (i < NN) ? deg[i] : 0;
    s[t] = v;
    __syncthreads();
    for (int off = 1; off < 256; off <<= 1) {
        int x = s[t];
        int y = (t >= off) ? s[t - off] : 0;
        __syncthreads();
        s[t] = x + y;
        __syncthreads();
    }
    int excl = s[t] - v + boffs[blockIdx.x];
    if (i < NN) {
        row_start[i] = excl;
        fill_pos[i] = excl;
    }
}

__global__ void fill_csr_kernel(const int* __restrict__ ei, int* __restrict__ fill_pos,
                                int* __restrict__ srcs) {
    int i = blockIdx.x * blockDim.x + threadIdx.x;
    if (i < EE) {
        int s = ei[i];
        int d = ei[EE + i];
        int p = atomicAdd(&fill_pos[d], 1);
        srcs[p] = s;
    } else if (i < ET) {
        int n = i - EE;
        int p = atomicAdd(&fill_pos[n], 1);
        srcs[p] = n;  // self loop
    }
}

// ---------------- casts ----------------

__global__ __launch_bounds__(256) void cast_x_kernel(const float* __restrict__ in,
                                                     ushortT* __restrict__ out) {
    int id = blockIdx.x * 256 + threadIdx.x;  // one float4 per thread
    float4 v = *(const float4*)(in + (size_t)id * 4);
    ushort4 o;
    o.x = f2b(v.x);
    o.y = f2b(v.y);
    o.z = f2b(v.z);
    o.w = f2b(v.w);
    *(ushort4*)(out + (size_t)id * 4) = o;
}

// Bt[n][k] = W[k][n], bf16 out. grid (8,8), block 256 (32x8)
__global__ __launch_bounds__(256) void castT_kernel(const float* __restrict__ W,
                                                    ushortT* __restrict__ Bt) {
    __shared__ float t[32][33];
    int bx = blockIdx.x * 32;  // k base
    int by = blockIdx.y * 32;  // n base
    int x = threadIdx.x & 31, y = threadIdx.x >> 5;
    for (int yy = y; yy < 32; yy += 8) t[yy][x] = W[(size_t)(bx + yy) * CD + by + x];
    __syncthreads();
    for (int yy = y; yy < 32; yy += 8)
        Bt[(size_t)(by + yy) * CD + bx + x] = f2b(t[x][yy]);
}

// straight cast (Wl: out = hB @ Wl^T -> Bt[n][k] = Wl[n][k] directly)
__global__ __launch_bounds__(256) void cast_w_kernel(const float* __restrict__ W,
                                                     ushortT* __restrict__ Bt) {
    int id = blockIdx.x * 256 + threadIdx.x;
    float4 v = *(const float4*)(W + (size_t)id * 4);
    ushort4 o;
    o.x = f2b(v.x);
    o.y = f2b(v.y);
    o.z = f2b(v.z);
    o.w = f2b(v.w);
    *(ushort4*)(Bt + (size_t)id * 4) = o;
}

// ---------------- bf16 MFMA GEMM: C[M,256] = A[M,256] @ Bt^T ----------------
// A row-major bf16 [M][256]; Bt n-major k-contiguous bf16 [256][256].
// OUTF32=1: fp32 out + bias. OUTF32=0: bf16 out, no bias.
// ALPHA=1: also accumulate as_[row] += C[row,:]@a_src, ad_[row] += C[row,:]@a_dst
// (partial over this block's 128 cols, atomicAdd across the 2 col-blocks),
// computed from the fp32 accumulator (matches reference better than bf16 h).

template <int OUTF32, int ALPHA>
__global__ __launch_bounds__(256) void gemm_mfma(const ushortT* __restrict__ A,
                                                 const ushortT* __restrict__ Bt,
                                                 const float* __restrict__ bias,
                                                 float* __restrict__ outF,
                                                 ushortT* __restrict__ outB,
                                                 const float* __restrict__ a_src,
                                                 const float* __restrict__ a_dst,
                                                 float* __restrict__ as_g,
                                                 float* __restrict__ ad_g,
                                                 int M) {
    __shared__ ushortT As[128 * 32];
    __shared__ ushortT Bs[128 * 32];
    int tid = threadIdx.x;
    int wave = tid >> 6, lane = tid & 63;
    int wm = (wave >> 1) * 64, wn = (wave & 1) * 64;
    int bm = blockIdx.x * 128, bn = blockIdx.y * 128;
    int l15 = lane & 15, quad = lane >> 4;

    f32x4 acc[4][4] = {};

    for (int k0 = 0; k0 < CD; k0 += 32) {
#pragma unroll
        for (int p = 0; p < 2; ++p) {
            int c = p * 256 + wave * 64 + lane;
            int row = c >> 2, piece = c & 3;
            const ushortT* ga = A + (size_t)(bm + row) * CD + k0 + piece * 8;
            const ushortT* gb = Bt + (size_t)(bn + row) * CD + k0 + piece * 8;
            // wave-uniform LDS base; HW scatters lane i to base + i*16
            __builtin_amdgcn_global_load_lds(
                (const __attribute__((address_space(1))) void*)ga,
                (__attribute__((address_space(3))) void*)(As + (size_t)(p * 256 + wave * 64) * 8),
                16, 0, 0);
            __builtin_amdgcn_global_load_lds(
                (const __attribute__((address_space(1))) void*)gb,
                (__attribute__((address_space(3))) void*)(Bs + (size_t)(p * 256 + wave * 64) * 8),
                16, 0, 0);
        }
        __syncthreads();

        bf16x8 a[4], b[4];
#pragma unroll
        for (int i = 0; i < 4; ++i)
            a[i] = *(const bf16x8*)(As + (size_t)(wm + i * 16 + l15) * 32 + quad * 8);
#pragma unroll
        for (int j = 0; j < 4; ++j)
            b[j] = *(const bf16x8*)(Bs + (size_t)(wn + j * 16 + l15) * 32 + quad * 8);
#pragma unroll
        for (int i = 0; i < 4; ++i)
#pragma unroll
            for (int j = 0; j < 4; ++j)
                acc[i][j] = __builtin_amdgcn_mfma_f32_16x16x32_bf16(a[i], b[j], acc[i][j], 0, 0, 0);
        __syncthreads();
    }

#pragma unroll
    for (int i = 0; i < 4; ++i) {
#pragma unroll
        for (int j = 0; j < 4; ++j) {
            int col = bn + wn + j * 16 + l15;
            int row0 = bm + wm + i * 16 + quad * 4;
#pragma unroll
            for (int r = 0; r < 4; ++r) {
                int row = row0 + r;
                if (row < M) {
                    float v = acc[i][j][r];
                    if (OUTF32) {
                        v += bias[col];
                        outF[(size_t)row * CD + col] = v;
                    } else {
                        outB[(size_t)row * CD + col] = f2b(v);
                    }
                }
            }
        }
    }

    if (ALPHA) {
        float avs[4], avd[4];
#pragma unroll
        for (int j = 0; j < 4; ++j) {
            int col = bn + wn + j * 16 + l15;
            avs[j] = a_src[col];
            avd[j] = a_dst[col];
        }
#pragma unroll
        for (int i = 0; i < 4; ++i) {
#pragma unroll
            for (int r = 0; r < 4; ++r) {
                int row = bm + wm + i * 16 + quad * 4 + r;
                float ps = 0.f, pd = 0.f;
#pragma unroll
                for (int j = 0; j < 4; ++j) {
                    float v = acc[i][j][r];
                    ps += v * avs[j];
                    pd += v * avd[j];
                }
                // reduce across the 16 lanes of this quad (xor stays in-quad)
#pragma unroll
                for (int off = 1; off < 16; off <<= 1) {
                    ps += __shfl_xor(ps, off);
                    pd += __shfl_xor(pd, off);
                }
                if (l15 == 0 && row < M) {
                    atomicAdd(&as_g[row], ps);
                    atomicAdd(&ad_g[row], pd);
                }
            }
        }
    }
}

// ---------------- GAT aggregation: one wave per dst node (bf16 h, bf16 out) ----------------

__device__ __forceinline__ float lrelu02(float x) { return x > 0.f ? x : 0.2f * x; }

__global__ __launch_bounds__(256) void gat_agg(const ushortT* __restrict__ h,
                                               const float* __restrict__ as_,
                                               const float* __restrict__ ad_,
                                               const int* __restrict__ row_start,
                                               const int* __restrict__ srcs,
                                               const float* __restrict__ bias,
                                               ushortT* __restrict__ out) {
    int node = blockIdx.x * 4 + (threadIdx.x >> 6);
    int lane = threadIdx.x & 63;
    if (node >= NN) return;
    int rs = row_start[node];
    int re = row_start[node + 1];
    int deg = re - rs;
    float adst = ad_[node];

    float a0 = 0.f, a1 = 0.f, a2 = 0.f, a3 = 0.f;

    if (deg <= 64) {
        // ---- fast path: softmax entirely in-register, ILP-8 gather ----
        int s_lane = srcs[rs + ((lane < deg) ? lane : 0)];
        float e = (lane < deg) ? lrelu02(as_[s_lane] + adst) : -1e30f;
        float m = e;
#pragma unroll
        for (int off = 1; off < 64; off <<= 1) m = fmaxf(m, __shfl_xor(m, off));
        float ex = (lane < deg) ? __expf(e - m) : 0.f;
        float den = ex;
#pragma unroll
        for (int off = 1; off < 64; off <<= 1) den += __shfl_xor(den, off);
        float wl = ex / den;  // per-lane edge weight (0 for invalid lanes)

        for (int kk = 0; kk < deg; kk += 8) {
            int s[8];
            float w[8];
#pragma unroll
            for (int t = 0; t < 8; ++t) {
                int idx = kk + t;                 // wave-uniform
                int ii = (idx < deg) ? idx : kk;  // clamp to a valid lane
                int sv = __shfl(s_lane, ii);
                float wv = __shfl(wl, ii);
                s[t] = sv;
                w[t] = (idx < deg) ? wv : 0.f;
            }
            ushort4 hv[8];
#pragma unroll
            for (int t = 0; t < 8; ++t)
                hv[t] = *(const ushort4*)(h + (size_t)s[t] * CD + lane * 4);
#pragma unroll
            for (int t = 0; t < 8; ++t) {
                a0 += w[t] * b2f(hv[t].x);
                a1 += w[t] * b2f(hv[t].y);
                a2 += w[t] * b2f(hv[t].z);
                a3 += w[t] * b2f(hv[t].w);
            }
        }
    } else {
        // ---- generic path (deg > 64): strided loops ----
        float m = -1e30f;
        for (int k = rs + lane; k < re; k += 64) {
            float e = lrelu02(as_[srcs[k]] + adst);
            m = fmaxf(m, e);
        }
#pragma unroll
        for (int off = 1; off < 64; off <<= 1) m = fmaxf(m, __shfl_xor(m, off));
        float den = 0.f;
        for (int k = rs + lane; k < re; k += 64) {
            float e = lrelu02(as_[srcs[k]] + adst);
            den += __expf(e - m);
        }
#pragma unroll
        for (int off = 1; off < 64; off <<= 1) den += __shfl_xor(den, off);
        float inv_den = 1.f / den;
        for (int k = rs; k < re; ++k) {
            int s = srcs[k];
            float e = lrelu02(as_[s] + adst);
            float w = __expf(e - m) * inv_den;
            ushort4 hv = *(const ushort4*)(h + (size_t)s * CD + lane * 4);
            a0 += w * b2f(hv.x);
            a1 += w * b2f(hv.y);
            a2 += w * b2f(hv.z);
            a3 += w * b2f(hv.w);
        }
    }

    float4 b4 = *(const float4*)(bias + lane * 4);
    a0 = fmaxf(a0 + b4.x, 0.f);  // bias + relu (both convs feed relu)
    a1 = fmaxf(a1 + b4.y, 0.f);
    a2 = fmaxf(a2 + b4.z, 0.f);
    a3 = fmaxf(a3 + b4.w, 0.f);
    ushort4 o;
    o.x = f2b(a0);
    o.y = f2b(a1);
    o.z = f2b(a2);
    o.w = f2b(a3);
    *(ushort4*)(out + (size_t)node * CD + lane * 4) = o;
}

// ---------------- launch ----------------

extern "C" void kernel_launch(void* const* d_in, const int* in_sizes, int n_in,
                              void* d_out, int out_size, void* d_ws, size_t ws_size,
                              hipStream_t stream) {
    const float* x = (const float*)d_in[0];
    const int* ei = (const int*)d_in[1];
    const float* W1 = (const float*)d_in[2];
    const float* a1s = (const float*)d_in[3];
    const float* a1d = (const float*)d_in[4];
    const float* b1 = (const float*)d_in[5];
    const float* W2 = (const float*)d_in[6];
    const float* a2s = (const float*)d_in[7];
    const float* a2d = (const float*)d_in[8];
    const float* b2 = (const float*)d_in[9];
    const float* Wl = (const float*)d_in[10];
    const float* bl = (const float*)d_in[11];
    float* out = (float*)d_out;

    char* w = (char*)d_ws;
    ushortT* B0 = (ushortT*)w; w += (size_t)PAD_M * CD * 2;
    ushortT* B1 = (ushortT*)w; w += (size_t)PAD_M * CD * 2;
    ushortT* B2 = (ushortT*)w; w += (size_t)PAD_M * CD * 2;
    ushortT* W1t = (ushortT*)w; w += (size_t)CD * CD * 2;
    ushortT* W2t = (ushortT*)w; w += (size_t)CD * CD * 2;
    ushortT* Wlt = (ushortT*)w; w += (size_t)CD * CD * 2;
    float* as_ = (float*)w; w += (size_t)NN * 4;
    float* ad_ = (float*)w; w += (size_t)NN * 4;
    int* deg = (int*)w; w += (size_t)NN * 4;
    int* fill_pos = (int*)w; w += (size_t)NN * 4;
    int* srcs = (int*)w; w += (size_t)ET * 4;
    int* bsum = (int*)w; w += 1024;
    int* boffs = (int*)w; w += 1024;
    int* row_start = (int*)w; w += (size_t)(NN + 1) * 4;

    // CSR build (+ zero alpha accumulators for layer-1 GEMM)
    init_kernel<<<(NN + 255) / 256, 256, 0, stream>>>(deg, as_, ad_);
    count_deg_kernel<<<(EE + 255) / 256, 256, 0, stream>>>(ei, deg);
    scan_part<<<NB, 256, 0, stream>>>(deg, bsum);
    scan_top<<<1, 256, 0, stream>>>(bsum, boffs, row_start);
    scan_fill<<<NB, 256, 0, stream>>>(deg, boffs, row_start, fill_pos);
    fill_csr_kernel<<<(ET + 255) / 256, 256, 0, stream>>>(ei, fill_pos, srcs);

    // casts
    cast_x_kernel<<<(NN * CD / 4) / 256, 256, 0, stream>>>(x, B0);
    castT_kernel<<<dim3(8, 8), 256, 0, stream>>>(W1, W1t);
    castT_kernel<<<dim3(8, 8), 256, 0, stream>>>(W2, W2t);
    cast_w_kernel<<<(CD * CD / 4) / 256, 256, 0, stream>>>(Wl, Wlt);

    dim3 ggrid((PAD_M) / 128, 2);
    int nwave_blocks = (NN + 3) / 4;

    // Layer 1 (alpha fused into GEMM epilogue)
    gemm_mfma<0, 1><<<ggrid, 256, 0, stream>>>(B0, W1t, nullptr, nullptr, B1,
                                               a1s, a1d, as_, ad_, NN);
    gat_agg<<<nwave_blocks, 256, 0, stream>>>(B1, as_, ad_, row_start, srcs, b1, B2);

    // Layer 2
    zero_alpha_kernel<<<(NN + 255) / 256, 256, 0, stream>>>(as_, ad_);
    gemm_mfma<0, 1><<<ggrid, 256, 0, stream>>>(B2, W2t, nullptr, nullptr, B1,
                                               a2s, a2d, as_, ad_, NN);
    gat_agg<<<nwave_blocks, 256, 0, stream>>>(B1, as_, ad_, row_start, srcs, b2, B0);

    // Final linear: out = B0 @ Wlt^T + bl (fp32 out)
    gemm_mfma<1, 0><<<ggrid, 256, 0, stream>>>(B0, Wlt, bl, out, nullptr,
                                               nullptr, nullptr, nullptr, nullptr, NN);
}

// Round 4
// 319.491 us; speedup vs baseline: 2.0710x; 1.0016x over previous
//
#include <hip/hip_runtime.h>

#define NN 50000
#define EE 300000
#define ET (EE + NN)   // edges + self loops = 350000
#define CD 256
#define PAD_M 50048    // 391 * 128, covers gemm tile over-read
#define NB 196         // scan blocks: 196*256 = 50176 >= NN

typedef unsigned short ushortT;
typedef short bf16x8 __attribute__((ext_vector_type(8)));
typedef float f32x4 __attribute__((ext_vector_type(4)));

__device__ __forceinline__ ushortT f2b(float f) {
    unsigned u = __builtin_bit_cast(unsigned, f);
    unsigned r = (u + 0x7FFFu + ((u >> 16) & 1u)) >> 16;
    return (ushortT)r;
}
__device__ __forceinline__ float b2f(ushortT b) {
    return __builtin_bit_cast(float, ((unsigned)b) << 16);
}

// ---------------- fused preprocessing ----------------
// flat grid of block roles:
//   [0,12500)        cast x -> B0 (bf16)
//   [12500,12564)    transpose-cast W1 -> W1t
//   [12564,12628)    transpose-cast W2 -> W2t
//   [12628,12692)    straight-cast Wl -> Wlt
//   [12692,12888)    init deg=1, zero alpha buffers (A and B sets)
#define PREP_X 12500
#define PREP_W1 12564
#define PREP_W2 12628
#define PREP_WL 12692
#define PREP_END 12888

__global__ __launch_bounds__(256) void prep_kernel(
    const float* __restrict__ x, const float* __restrict__ W1,
    const float* __restrict__ W2, const float* __restrict__ Wl,
    ushortT* __restrict__ B0, ushortT* __restrict__ W1t,
    ushortT* __restrict__ W2t, ushortT* __restrict__ Wlt,
    int* __restrict__ deg, float* __restrict__ asA, float* __restrict__ adA,
    float* __restrict__ asB, float* __restrict__ adB) {
    __shared__ float t[32][33];
    int b = blockIdx.x, tidx = threadIdx.x;
    if (b < PREP_X) {
        int id = b * 256 + tidx;
        float4 v = *(const float4*)(x + (size_t)id * 4);
        ushort4 o;
        o.x = f2b(v.x); o.y = f2b(v.y); o.z = f2b(v.z); o.w = f2b(v.w);
        *(ushort4*)(B0 + (size_t)id * 4) = o;
    } else if (b < PREP_W2) {
        const float* W = (b < PREP_W1) ? W1 : W2;
        ushortT* Bt = (b < PREP_W1) ? W1t : W2t;
        int rel = b - ((b < PREP_W1) ? PREP_X : PREP_W1);
        int bx = (rel & 7) * 32;   // k base
        int by = (rel >> 3) * 32;  // n base
        int xx = tidx & 31, yy = tidx >> 5;
        for (int y = yy; y < 32; y += 8) t[y][xx] = W[(size_t)(bx + y) * CD + by + xx];
        __syncthreads();
        for (int y = yy; y < 32; y += 8)
            Bt[(size_t)(by + y) * CD + bx + xx] = f2b(t[xx][y]);
    } else if (b < PREP_WL) {
        int id = (b - PREP_W2) * 256 + tidx;
        float4 v = *(const float4*)(Wl + (size_t)id * 4);
        ushort4 o;
        o.x = f2b(v.x); o.y = f2b(v.y); o.z = f2b(v.z); o.w = f2b(v.w);
        *(ushort4*)(Wlt + (size_t)id * 4) = o;
    } else {
        int i = (b - PREP_WL) * 256 + tidx;
        if (i < NN) {
            deg[i] = 1;  // self loop
            asA[i] = 0.f; adA[i] = 0.f;
            asB[i] = 0.f; adB[i] = 0.f;
        }
    }
}

// ---------------- CSR build ----------------

__global__ void count_deg_kernel(const int* __restrict__ ei, int* __restrict__ deg) {
    int i = blockIdx.x * blockDim.x + threadIdx.x;
    if (i < EE) atomicAdd(&deg[ei[EE + i]], 1);  // dst row of edge_index
}

__global__ __launch_bounds__(256) void scan_part(const int* __restrict__ deg,
                                                 int* __restrict__ bsum) {
    int i = blockIdx.x * 256 + threadIdx.x;
    int v = (i < NN) ? deg[i] : 0;
#pragma unroll
    for (int off = 32; off > 0; off >>= 1) v += __shfl_down(v, off);
    __shared__ int w[4];
    if ((threadIdx.x & 63) == 0) w[threadIdx.x >> 6] = v;
    __syncthreads();
    if (threadIdx.x == 0) bsum[blockIdx.x] = w[0] + w[1] + w[2] + w[3];
}

__global__ __launch_bounds__(256) void scan_top(const int* __restrict__ bsum,
                                                int* __restrict__ boffs,
                                                int* __restrict__ row_start) {
    __shared__ int s[256];
    int t = threadIdx.x;
    int v = (t < NB) ? bsum[t] : 0;
    s[t] = v;
    __syncthreads();
    for (int off = 1; off < 256; off <<= 1) {
        int x = s[t];
        int y = (t >= off) ? s[t - off] : 0;
        __syncthreads();
        s[t] = x + y;
        __syncthreads();
    }
    if (t < NB) boffs[t] = s[t] - v;  // exclusive
    if (t == 0) row_start[NN] = ET;
}

__global__ __launch_bounds__(256) void scan_fill(const int* __restrict__ deg,
                                                 const int* __restrict__ boffs,
                                                 int* __restrict__ row_start,
                                                 int* __restrict__ fill_pos) {
    __shared__ int s[256];
    int t = threadIdx.x;
    int i = blockIdx.x * 256 + t;
    int v = (i < NN) ? deg[i] : 0;
    s[t] = v;
    __syncthreads();
    for (int off = 1; off < 256; off <<= 1) {
        int x = s[t];
        int y = (t >= off) ? s[t - off] : 0;
        __syncthreads();
        s[t] = x + y;
        __syncthreads();
    }
    int excl = s[t] - v + boffs[blockIdx.x];
    if (i < NN) {
        row_start[i] = excl;
        fill_pos[i] = excl;
    }
}

__global__ void fill_csr_kernel(const int* __restrict__ ei, int* __restrict__ fill_pos,
                                int* __restrict__ srcs) {
    int i = blockIdx.x * blockDim.x + threadIdx.x;
    if (i < EE) {
        int s = ei[i];
        int d = ei[EE + i];
        int p = atomicAdd(&fill_pos[d], 1);
        srcs[p] = s;
    } else if (i < ET) {
        int n = i - EE;
        int p = atomicAdd(&fill_pos[n], 1);
        srcs[p] = n;  // self loop
    }
}

// ---------------- bf16 MFMA GEMM: C[M,256] = A[M,256] @ Bt^T ----------------
// A row-major bf16 [M][256]; Bt n-major k-contiguous bf16 [256][256].
// Structure: this block's 128-col B slice (64 KB) staged ONCE into LDS
// (xor-swizzled 16B chunks to kill bank conflicts), then a barrier-free
// K-loop with A fragments loaded global->register directly.
// OUTF32=1: fp32 out + bias. OUTF32=0: bf16 out (unconditional store into
// padded ws buffer), no bias.
// ALPHA=1: as_[row] += C[row,:]@a_src etc. from the fp32 accumulator.

template <int OUTF32, int ALPHA>
__global__ __launch_bounds__(256) void gemm_mfma(const ushortT* __restrict__ A,
                                                 const ushortT* __restrict__ Bt,
                                                 const float* __restrict__ bias,
                                                 float* __restrict__ outF,
                                                 ushortT* __restrict__ outB,
                                                 const float* __restrict__ a_src,
                                                 const float* __restrict__ a_dst,
                                                 float* __restrict__ as_g,
                                                 float* __restrict__ ad_g,
                                                 int M) {
    __shared__ ushortT Bs[128 * 256];  // 64 KB, n-major, 16B-chunk xor-swizzle
    int tid = threadIdx.x;
    int wave = tid >> 6, lane = tid & 63;
    int wm = (wave >> 1) * 64, wn = (wave & 1) * 64;
    int bm = blockIdx.x * 128, bn = blockIdx.y * 128;
    int l15 = lane & 15, quad = lane >> 4;

    // ---- stage full B slice: 4096 16B chunks, 16 rounds of 256 threads ----
#pragma unroll
    for (int p = 0; p < 16; ++p) {
        int c = p * 256 + wave * 64 + lane;   // flat chunk id (lane-linear)
        int row = c >> 5;                      // 32 chunks per 256-elem row
        int piece = c & 31;
        int spiece = piece ^ (row & 31);       // xor-swizzle source chunk
        const ushortT* gb = Bt + (size_t)(bn + row) * CD + spiece * 8;
        __builtin_amdgcn_global_load_lds(
            (const __attribute__((address_space(1))) void*)gb,
            (__attribute__((address_space(3))) void*)(Bs + (size_t)(p * 256 + wave * 64) * 8),
            16, 0, 0);
    }
    __syncthreads();

    f32x4 acc[4][4] = {};

    // ---- barrier-free K loop: 8 x K32 steps ----
#pragma unroll
    for (int kk = 0; kk < 8; ++kk) {
        bf16x8 a[4], b[4];
#pragma unroll
        for (int i = 0; i < 4; ++i)
            a[i] = *(const bf16x8*)(A + (size_t)(bm + wm + i * 16 + l15) * CD + kk * 32 + quad * 8);
        int kc = kk * 4 + quad;  // 16B chunk index within row
#pragma unroll
        for (int j = 0; j < 4; ++j) {
            int n_local = wn + j * 16 + l15;
            b[j] = *(const bf16x8*)(Bs + (size_t)n_local * 256 + (size_t)(kc ^ (n_local & 31)) * 8);
        }
#pragma unroll
        for (int i = 0; i < 4; ++i)
#pragma unroll
            for (int j = 0; j < 4; ++j)
                acc[i][j] = __builtin_amdgcn_mfma_f32_16x16x32_bf16(a[i], b[j], acc[i][j], 0, 0, 0);
    }

    // ---- epilogue ----
#pragma unroll
    for (int i = 0; i < 4; ++i) {
#pragma unroll
        for (int j = 0; j < 4; ++j) {
            int col = bn + wn + j * 16 + l15;
            int row0 = bm + wm + i * 16 + quad * 4;
#pragma unroll
            for (int r = 0; r < 4; ++r) {
                int row = row0 + r;
                float v = acc[i][j][r];
                if (OUTF32) {
                    if (row < M) outF[(size_t)row * CD + col] = v + bias[col];
                } else {
                    outB[(size_t)row * CD + col] = f2b(v);  // ws padded, no check
                }
            }
        }
    }

    if (ALPHA) {
        float avs[4], avd[4];
#pragma unroll
        for (int j = 0; j < 4; ++j) {
            int col = bn + wn + j * 16 + l15;
            avs[j] = a_src[col];
            avd[j] = a_dst[col];
        }
#pragma unroll
        for (int i = 0; i < 4; ++i) {
#pragma unroll
            for (int r = 0; r < 4; ++r) {
                int row = bm + wm + i * 16 + quad * 4 + r;
                float ps = 0.f, pd = 0.f;
#pragma unroll
                for (int j = 0; j < 4; ++j) {
                    float v = acc[i][j][r];
                    ps += v * avs[j];
                    pd += v * avd[j];
                }
#pragma unroll
                for (int off = 1; off < 16; off <<= 1) {  // xor stays in-quad
                    ps += __shfl_xor(ps, off);
                    pd += __shfl_xor(pd, off);
                }
                if (l15 == 0 && row < M) {
                    atomicAdd(&as_g[row], ps);
                    atomicAdd(&ad_g[row], pd);
                }
            }
        }
    }
}

// ---------------- GAT aggregation: one wave per dst node (bf16 h, bf16 out) ----------------

__device__ __forceinline__ float lrelu02(float x) { return x > 0.f ? x : 0.2f * x; }

__global__ __launch_bounds__(256) void gat_agg(const ushortT* __restrict__ h,
                                               const float* __restrict__ as_,
                                               const float* __restrict__ ad_,
                                               const int* __restrict__ row_start,
                                               const int* __restrict__ srcs,
                                               const float* __restrict__ bias,
                                               ushortT* __restrict__ out) {
    int node = blockIdx.x * 4 + (threadIdx.x >> 6);
    int lane = threadIdx.x & 63;
    if (node >= NN) return;
    int rs = row_start[node];
    int re = row_start[node + 1];
    int deg = re - rs;
    float adst = ad_[node];

    float a0 = 0.f, a1 = 0.f, a2 = 0.f, a3 = 0.f;

    if (deg <= 64) {
        // ---- fast path: softmax entirely in-register, ILP-8 gather ----
        int s_lane = srcs[rs + ((lane < deg) ? lane : 0)];
        float e = (lane < deg) ? lrelu02(as_[s_lane] + adst) : -1e30f;
        float m = e;
#pragma unroll
        for (int off = 1; off < 64; off <<= 1) m = fmaxf(m, __shfl_xor(m, off));
        float ex = (lane < deg) ? __expf(e - m) : 0.f;
        float den = ex;
#pragma unroll
        for (int off = 1; off < 64; off <<= 1) den += __shfl_xor(den, off);
        float wl = ex / den;  // per-lane edge weight (0 for invalid lanes)

        for (int kk = 0; kk < deg; kk += 8) {
            int s[8];
            float w[8];
#pragma unroll
            for (int t = 0; t < 8; ++t) {
                int idx = kk + t;                 // wave-uniform
                int ii = (idx < deg) ? idx : kk;  // clamp to a valid lane
                int sv = __shfl(s_lane, ii);
                float wv = __shfl(wl, ii);
                s[t] = sv;
                w[t] = (idx < deg) ? wv : 0.f;
            }
            ushort4 hv[8];
#pragma unroll
            for (int t = 0; t < 8; ++t)
                hv[t] = *(const ushort4*)(h + (size_t)s[t] * CD + lane * 4);
#pragma unroll
            for (int t = 0; t < 8; ++t) {
                a0 += w[t] * b2f(hv[t].x);
                a1 += w[t] * b2f(hv[t].y);
                a2 += w[t] * b2f(hv[t].z);
                a3 += w[t] * b2f(hv[t].w);
            }
        }
    } else {
        // ---- generic path (deg > 64): strided loops ----
        float m = -1e30f;
        for (int k = rs + lane; k < re; k += 64) {
            float e = lrelu02(as_[srcs[k]] + adst);
            m = fmaxf(m, e);
        }
#pragma unroll
        for (int off = 1; off < 64; off <<= 1) m = fmaxf(m, __shfl_xor(m, off));
        float den = 0.f;
        for (int k = rs + lane; k < re; k += 64) {
            float e = lrelu02(as_[srcs[k]] + adst);
            den += __expf(e - m);
        }
#pragma unroll
        for (int off = 1; off < 64; off <<= 1) den += __shfl_xor(den, off);
        float inv_den = 1.f / den;
        for (int k = rs; k < re; ++k) {
            int s = srcs[k];
            float e = lrelu02(as_[s] + adst);
            float w = __expf(e - m) * inv_den;
            ushort4 hv = *(const ushort4*)(h + (size_t)s * CD + lane * 4);
            a0 += w * b2f(hv.x);
            a1 += w * b2f(hv.y);
            a2 += w * b2f(hv.z);
            a3 += w * b2f(hv.w);
        }
    }

    float4 b4 = *(const float4*)(bias + lane * 4);
    a0 = fmaxf(a0 + b4.x, 0.f);  // bias + relu (both convs feed relu)
    a1 = fmaxf(a1 + b4.y, 0.f);
    a2 = fmaxf(a2 + b4.z, 0.f);
    a3 = fmaxf(a3 + b4.w, 0.f);
    ushort4 o;
    o.x = f2b(a0);
    o.y = f2b(a1);
    o.z = f2b(a2);
    o.w = f2b(a3);
    *(ushort4*)(out + (size_t)node * CD + lane * 4) = o;
}

// ---------------- launch ----------------

extern "C" void kernel_launch(void* const* d_in, const int* in_sizes, int n_in,
                              void* d_out, int out_size, void* d_ws, size_t ws_size,
                              hipStream_t stream) {
    const float* x = (const float*)d_in[0];
    const int* ei = (const int*)d_in[1];
    const float* W1 = (const float*)d_in[2];
    const float* a1s = (const float*)d_in[3];
    const float* a1d = (const float*)d_in[4];
    const float* b1 = (const float*)d_in[5];
    const float* W2 = (const float*)d_in[6];
    const float* a2s = (const float*)d_in[7];
    const float* a2d = (const float*)d_in[8];
    const float* b2 = (const float*)d_in[9];
    const float* Wl = (const float*)d_in[10];
    const float* bl = (const float*)d_in[11];
    float* out = (float*)d_out;

    char* w = (char*)d_ws;
    ushortT* B0 = (ushortT*)w; w += (size_t)PAD_M * CD * 2;
    ushortT* B1 = (ushortT*)w; w += (size_t)PAD_M * CD * 2;
    ushortT* B2 = (ushortT*)w; w += (size_t)PAD_M * CD * 2;
    ushortT* W1t = (ushortT*)w; w += (size_t)CD * CD * 2;
    ushortT* W2t = (ushortT*)w; w += (size_t)CD * CD * 2;
    ushortT* Wlt = (ushortT*)w; w += (size_t)CD * CD * 2;
    float* asA = (float*)w; w += (size_t)NN * 4;
    float* adA = (float*)w; w += (size_t)NN * 4;
    float* asB = (float*)w; w += (size_t)NN * 4;
    float* adB = (float*)w; w += (size_t)NN * 4;
    int* deg = (int*)w; w += (size_t)NN * 4;
    int* fill_pos = (int*)w; w += (size_t)NN * 4;
    int* srcs = (int*)w; w += (size_t)ET * 4;
    int* bsum = (int*)w; w += 1024;
    int* boffs = (int*)w; w += 1024;
    int* row_start = (int*)w; w += (size_t)(NN + 1) * 4;

    // fused preprocessing: casts + deg/alpha init
    prep_kernel<<<PREP_END, 256, 0, stream>>>(x, W1, W2, Wl, B0, W1t, W2t, Wlt,
                                              deg, asA, adA, asB, adB);

    // CSR build
    count_deg_kernel<<<(EE + 255) / 256, 256, 0, stream>>>(ei, deg);
    scan_part<<<NB, 256, 0, stream>>>(deg, bsum);
    scan_top<<<1, 256, 0, stream>>>(bsum, boffs, row_start);
    scan_fill<<<NB, 256, 0, stream>>>(deg, boffs, row_start, fill_pos);
    fill_csr_kernel<<<(ET + 255) / 256, 256, 0, stream>>>(ei, fill_pos, srcs);

    dim3 ggrid((PAD_M) / 128, 2);
    int nwave_blocks = (NN + 3) / 4;

    // Layer 1 (alpha fused into GEMM epilogue, A buffers)
    gemm_mfma<0, 1><<<ggrid, 256, 0, stream>>>(B0, W1t, nullptr, nullptr, B1,
                                               a1s, a1d, asA, adA, NN);
    gat_agg<<<nwave_blocks, 256, 0, stream>>>(B1, asA, adA, row_start, srcs, b1, B2);

    // Layer 2 (B buffers — pre-zeroed in prep, no zero dispatch needed)
    gemm_mfma<0, 1><<<ggrid, 256, 0, stream>>>(B2, W2t, nullptr, nullptr, B1,
                                               a2s, a2d, asB, adB, NN);
    gat_agg<<<nwave_blocks, 256, 0, stream>>>(B1, asB, adB, row_start, srcs, b2, B0);

    // Final linear: out = B0 @ Wlt^T + bl (fp32 out)
    gemm_mfma<1, 0><<<ggrid, 256, 0, stream>>>(B0, Wlt, bl, out, nullptr,
                                               nullptr, nullptr, nullptr, nullptr, NN);
}